// Round 2
// baseline (1505.376 us; speedup 1.0000x reference)
//
#include <hip/hip_runtime.h>
#include <stdint.h>
#include <stddef.h>

// ---------- types & helpers ----------
typedef __bf16 bf16x8 __attribute__((ext_vector_type(8)));
typedef float  f32x4  __attribute__((ext_vector_type(4)));

static __device__ __forceinline__ float bf2f(unsigned short u) {
    union { unsigned int i; float f; } v; v.i = ((unsigned int)u) << 16; return v.f;
}
static __device__ __forceinline__ unsigned short f2bf(float f) {
    union { float f; unsigned int i; } v; v.f = f;
    unsigned int r = v.i + 0x7FFFu + ((v.i >> 16) & 1u);
    return (unsigned short)(r >> 16);
}

#define N_NODES 100000
#define N_EDGES 3200000
#define MPAD    100096   // multiple of 128

// ---------- CSR build ----------
__global__ __launch_bounds__(256) void hist_k(const int* __restrict__ er, int* __restrict__ cnt, int E) {
    int i = blockIdx.x * 256 + threadIdx.x;
    if (i < E) atomicAdd(&cnt[er[i]], 1);
}

// writes rp (CSR offsets) AND cur (scatter cursors) — copy_k folded in
__global__ __launch_bounds__(1024) void scan_k(const int* __restrict__ cnt, int* __restrict__ rp,
                                               int* __restrict__ cur, int N, int E) {
    __shared__ int sums[1024];
    int tid = threadIdx.x;
    int chunk = (N + 1023) >> 10;           // 98
    int lo = tid * chunk;
    int hi = lo + chunk; if (hi > N) hi = N;
    int s = 0;
    for (int i = lo; i < hi; i++) s += cnt[i];
    sums[tid] = s;
    __syncthreads();
    for (int off = 1; off < 1024; off <<= 1) {
        int v = (tid >= off) ? sums[tid - off] : 0;
        __syncthreads();
        sums[tid] += v;
        __syncthreads();
    }
    int run = (tid == 0) ? 0 : sums[tid - 1];
    for (int i = lo; i < hi; i++) { rp[i] = run; cur[i] = run; run += cnt[i]; }
    if (tid == 0) rp[N] = E;
}

// packed (col, val) scatter: ONE 8-byte store per edge instead of two 4-byte
__global__ __launch_bounds__(256) void scatter_k(const int* __restrict__ er, const int* __restrict__ ec,
                                                 const float* __restrict__ ev, int* __restrict__ cur,
                                                 int2* __restrict__ cpack, int E) {
    int i = blockIdx.x * 256 + threadIdx.x;
    if (i < E) {
        int r = er[i];
        int p = atomicAdd(&cur[r], 1);
        cpack[p] = make_int2(ec[i], __float_as_int(ev[i]));
    }
}

// ---------- weight transpose + bf16 convert:  W[K][Nc] -> Wt[Nc][K] ----------
__global__ __launch_bounds__(256) void transpose_k(const float* __restrict__ W, unsigned short* __restrict__ Wt,
                                                   int K, int Nc) {
    int i = blockIdx.x * 256 + threadIdx.x;
    if (i < K * Nc) {
        int k = i / Nc, n = i % Nc;
        Wt[(size_t)n * K + k] = f2bf(W[i]);
    }
}

// ---------- MFMA GEMM: C[Mpad][Nc](bf16) = A[Mpad][K] @ Bt[Nc][K]^T ----------
template<int BM, int BN, int BK, bool A_F32>
__global__ __launch_bounds__(256) void gemm_mfma(const void* __restrict__ Aptr,
                                                 const unsigned short* __restrict__ Bt,
                                                 unsigned short* __restrict__ C,
                                                 int K, int Nc, int Mclamp) {
    constexpr int WROWS = 2, WCOLS = 2;
    constexpr int WM = BM / WROWS, WN = BN / WCOLS;
    constexpr int MT = WM / 16, NT = WN / 16;
    constexpr int LDA = BK + 8;             // elems; row stride multiple of 16B
    constexpr int KV = BK / 8;

    __shared__ unsigned short lds_a[BM * LDA];
    __shared__ unsigned short lds_b[BN * LDA];

    const int tid  = threadIdx.x;
    const int wid  = tid >> 6, lane = tid & 63;
    const int wrow = wid >> 1, wcol = wid & 1;
    const int bm = blockIdx.x * BM, bn = blockIdx.y * BN;
    const int r = lane & 15, q = lane >> 4;

    const float*          Af = (const float*)Aptr;
    const unsigned short* Ab = (const unsigned short*)Aptr;

    f32x4 acc[MT][NT];
    f32x4 zero = {0.f, 0.f, 0.f, 0.f};
#pragma unroll
    for (int mi = 0; mi < MT; mi++)
#pragma unroll
        for (int ni = 0; ni < NT; ni++) acc[mi][ni] = zero;

    for (int k0 = 0; k0 < K; k0 += BK) {
#pragma unroll
        for (int it = 0; it < (BM * KV) / 256; it++) {
            int v = tid + it * 256;
            int row = v / KV, kc = (v % KV) * 8;
            int grow = bm + row;
            uint4 d;
            if constexpr (A_F32) {
                grow = (grow <= Mclamp) ? grow : Mclamp;
                const float4* pp = (const float4*)(Af + (size_t)grow * K + k0 + kc);
                float4 f0 = pp[0], f1 = pp[1];
                d.x = (unsigned)f2bf(f0.x) | ((unsigned)f2bf(f0.y) << 16);
                d.y = (unsigned)f2bf(f0.z) | ((unsigned)f2bf(f0.w) << 16);
                d.z = (unsigned)f2bf(f1.x) | ((unsigned)f2bf(f1.y) << 16);
                d.w = (unsigned)f2bf(f1.z) | ((unsigned)f2bf(f1.w) << 16);
            } else {
                d = *(const uint4*)(Ab + (size_t)grow * K + k0 + kc);
            }
            *(uint4*)&lds_a[row * LDA + kc] = d;
        }
#pragma unroll
        for (int it = 0; it < (BN * KV) / 256; it++) {
            int v = tid + it * 256;
            int row = v / KV, kc = (v % KV) * 8;
            uint4 d = *(const uint4*)(Bt + (size_t)(bn + row) * K + k0 + kc);
            *(uint4*)&lds_b[row * LDA + kc] = d;
        }
        __syncthreads();

#pragma unroll
        for (int kk = 0; kk < BK; kk += 32) {
            bf16x8 av[MT], bv[NT];
#pragma unroll
            for (int mi = 0; mi < MT; mi++)
                av[mi] = *(const bf16x8*)&lds_a[(wrow * WM + mi * 16 + r) * LDA + kk + q * 8];
#pragma unroll
            for (int ni = 0; ni < NT; ni++)
                bv[ni] = *(const bf16x8*)&lds_b[(wcol * WN + ni * 16 + r) * LDA + kk + q * 8];
#pragma unroll
            for (int mi = 0; mi < MT; mi++)
#pragma unroll
                for (int ni = 0; ni < NT; ni++)
                    acc[mi][ni] = __builtin_amdgcn_mfma_f32_16x16x32_bf16(av[mi], bv[ni], acc[mi][ni], 0, 0, 0);
        }
        __syncthreads();
    }

    // epilogue: C/D layout col = lane&15, row = q*4 + d
#pragma unroll
    for (int mi = 0; mi < MT; mi++) {
        int row = bm + wrow * WM + mi * 16 + q * 4;
#pragma unroll
        for (int ni = 0; ni < NT; ni++) {
            int cc = bn + wcol * WN + ni * 16 + r;
#pragma unroll
            for (int d = 0; d < 4; d++)
                C[(size_t)(row + d) * Nc + cc] = f2bf(acc[mi][ni][d]);
        }
    }
}

// ---------- SPMM (F=256): one wave per row, lane owns 4 features ----------
__global__ __launch_bounds__(256) void spmm_f256(const int* __restrict__ rp, const int2* __restrict__ cpack,
                                                 const unsigned short* __restrict__ Z,
                                                 const float* __restrict__ bias, unsigned short* __restrict__ H, int N) {
    int w = (blockIdx.x * 256 + threadIdx.x) >> 6;
    if (w >= N) return;
    int lane = threadIdx.x & 63;
    int f0 = lane * 4;
    int s = rp[w], e = rp[w + 1];
    float a0 = 0.f, a1 = 0.f, a2 = 0.f, a3 = 0.f;
    int j = s;
    for (; j + 4 <= e; j += 4) {
        int2 e0 = cpack[j], e1 = cpack[j + 1], e2 = cpack[j + 2], e3 = cpack[j + 3];
        ushort4 z0 = *(const ushort4*)(Z + (size_t)e0.x * 256 + f0);
        ushort4 z1 = *(const ushort4*)(Z + (size_t)e1.x * 256 + f0);
        ushort4 z2 = *(const ushort4*)(Z + (size_t)e2.x * 256 + f0);
        ushort4 z3 = *(const ushort4*)(Z + (size_t)e3.x * 256 + f0);
        float w0 = __int_as_float(e0.y), w1 = __int_as_float(e1.y);
        float w2 = __int_as_float(e2.y), w3 = __int_as_float(e3.y);
        a0 += w0 * bf2f(z0.x); a1 += w0 * bf2f(z0.y); a2 += w0 * bf2f(z0.z); a3 += w0 * bf2f(z0.w);
        a0 += w1 * bf2f(z1.x); a1 += w1 * bf2f(z1.y); a2 += w1 * bf2f(z1.z); a3 += w1 * bf2f(z1.w);
        a0 += w2 * bf2f(z2.x); a1 += w2 * bf2f(z2.y); a2 += w2 * bf2f(z2.z); a3 += w2 * bf2f(z2.w);
        a0 += w3 * bf2f(z3.x); a1 += w3 * bf2f(z3.y); a2 += w3 * bf2f(z3.z); a3 += w3 * bf2f(z3.w);
    }
    for (; j < e; j++) {
        int2 e0 = cpack[j];
        float w0 = __int_as_float(e0.y);
        ushort4 z0 = *(const ushort4*)(Z + (size_t)e0.x * 256 + f0);
        a0 += w0 * bf2f(z0.x); a1 += w0 * bf2f(z0.y); a2 += w0 * bf2f(z0.z); a3 += w0 * bf2f(z0.w);
    }
    float4 b = *(const float4*)(bias + f0);
    a0 = fmaxf(a0 + b.x, 0.f); a1 = fmaxf(a1 + b.y, 0.f);
    a2 = fmaxf(a2 + b.z, 0.f); a3 = fmaxf(a3 + b.w, 0.f);
    ushort4 o; o.x = f2bf(a0); o.y = f2bf(a1); o.z = f2bf(a2); o.w = f2bf(a3);
    *(ushort4*)(H + (size_t)w * 256 + f0) = o;
}

// ---------- SPMM (F=64) + bias + log_softmax fused ----------
__global__ __launch_bounds__(256) void spmm_f64_lsm(const int* __restrict__ rp, const int2* __restrict__ cpack,
                                                    const unsigned short* __restrict__ Z,
                                                    const float* __restrict__ bias, float* __restrict__ out, int N) {
    int w = (blockIdx.x * 256 + threadIdx.x) >> 6;
    if (w >= N) return;
    int lane = threadIdx.x & 63;
    int s = rp[w], e = rp[w + 1];
    float a = 0.f;
    int j = s;
    for (; j + 4 <= e; j += 4) {
        int2 e0 = cpack[j], e1 = cpack[j + 1], e2 = cpack[j + 2], e3 = cpack[j + 3];
        float z0 = bf2f(Z[(size_t)e0.x * 64 + lane]);
        float z1 = bf2f(Z[(size_t)e1.x * 64 + lane]);
        float z2 = bf2f(Z[(size_t)e2.x * 64 + lane]);
        float z3 = bf2f(Z[(size_t)e3.x * 64 + lane]);
        a += __int_as_float(e0.y) * z0 + __int_as_float(e1.y) * z1;
        a += __int_as_float(e2.y) * z2 + __int_as_float(e3.y) * z3;
    }
    for (; j < e; j++) {
        int2 e0 = cpack[j];
        a += __int_as_float(e0.y) * bf2f(Z[(size_t)e0.x * 64 + lane]);
    }
    a += bias[lane];
    float m = a;
    for (int off = 32; off >= 1; off >>= 1) m = fmaxf(m, __shfl_xor(m, off, 64));
    float ex = __expf(a - m);
    float sum = ex;
    for (int off = 32; off >= 1; off >>= 1) sum += __shfl_xor(sum, off, 64);
    out[(size_t)w * 64 + lane] = a - m - __logf(sum);
}

// ---------- launch ----------
extern "C" void kernel_launch(void* const* d_in, const int* in_sizes, int n_in,
                              void* d_out, int out_size, void* d_ws, size_t ws_size,
                              hipStream_t stream) {
    const float* x  = (const float*)d_in[0];
    const int*   er = (const int*)  d_in[1];
    const int*   ec = (const int*)  d_in[2];
    const float* ev = (const float*)d_in[3];
    const float* W1 = (const float*)d_in[4];
    const float* b1 = (const float*)d_in[5];
    const float* W2 = (const float*)d_in[6];
    const float* b2 = (const float*)d_in[7];
    const float* W3 = (const float*)d_in[8];
    const float* b3 = (const float*)d_in[9];

    const int N = N_NODES, E = N_EDGES;

    char* p = (char*)d_ws;
    auto alloc = [&](size_t bytes) -> char* {
        char* q = p; p += (bytes + 255) & ~(size_t)255; return q;
    };
    unsigned short* Wt1  = (unsigned short*)alloc((size_t)256 * 512 * 2);
    unsigned short* Wt2  = (unsigned short*)alloc((size_t)256 * 256 * 2);
    unsigned short* Wt3  = (unsigned short*)alloc((size_t)64  * 256 * 2);
    int*            rp   = (int*)  alloc((size_t)(N + 1) * 4);
    int*            cnt  = (int*)  alloc((size_t)N * 4);
    int*            cur  = (int*)  alloc((size_t)N * 4);
    int2*           cpack= (int2*) alloc((size_t)E * 8);
    unsigned short* bufA = (unsigned short*)alloc((size_t)MPAD * 256 * 2);
    unsigned short* bufB = (unsigned short*)alloc((size_t)MPAD * 256 * 2);

    // CSR build
    hipMemsetAsync(cnt, 0, (size_t)N * 4, stream);
    hist_k   <<<(E + 255) / 256, 256, 0, stream>>>(er, cnt, E);
    scan_k   <<<1, 1024, 0, stream>>>(cnt, rp, cur, N, E);
    scatter_k<<<(E + 255) / 256, 256, 0, stream>>>(er, ec, ev, cur, cpack, E);

    // weights -> bf16 transposed
    transpose_k<<<(512 * 256) / 256, 256, 0, stream>>>(W1, Wt1, 512, 256);
    transpose_k<<<(256 * 256) / 256, 256, 0, stream>>>(W2, Wt2, 256, 256);
    transpose_k<<<(256 * 64)  / 256, 256, 0, stream>>>(W3, Wt3, 256, 64);

    // layer 1: Z = x @ W1 ; H = relu(spmm(Z) + b1)
    gemm_mfma<64, 256, 64, true ><<<dim3(MPAD / 64, 1), 256, 0, stream>>>(x,    Wt1, bufA, 512, 256, N - 1);
    spmm_f256<<<N / 4, 256, 0, stream>>>(rp, cpack, bufA, b1, bufB, N);
    // layer 2
    gemm_mfma<64, 256, 64, false><<<dim3(MPAD / 64, 1), 256, 0, stream>>>(bufB, Wt2, bufA, 256, 256, N - 1);
    spmm_f256<<<N / 4, 256, 0, stream>>>(rp, cpack, bufA, b2, bufB, N);
    // layer 3 (+ fused bias + log_softmax)
    gemm_mfma<128, 64, 64, false><<<dim3(MPAD / 128, 1), 256, 0, stream>>>(bufB, Wt3, bufA, 256, 64, N - 1);
    spmm_f64_lsm<<<N / 4, 256, 0, stream>>>(rp, cpack, bufA, b3, (float*)d_out, N);
}

// Round 3
// 1058.532 us; speedup vs baseline: 1.4221x; 1.4221x over previous
//
#include <hip/hip_runtime.h>
#include <stdint.h>
#include <stddef.h>

// ---------- types & helpers ----------
typedef __bf16 bf16x8 __attribute__((ext_vector_type(8)));
typedef float  f32x4  __attribute__((ext_vector_type(4)));

static __device__ __forceinline__ float bf2f(unsigned short u) {
    union { unsigned int i; float f; } v; v.i = ((unsigned int)u) << 16; return v.f;
}
static __device__ __forceinline__ unsigned short f2bf(float f) {
    union { float f; unsigned int i; } v; v.f = f;
    unsigned int r = v.i + 0x7FFFu + ((v.i >> 16) & 1u);
    return (unsigned short)(r >> 16);
}

#define N_NODES 100000
#define N_EDGES 3200000
#define MPAD    100096      // multiple of 128
#define NB      782         // buckets of 128 rows: ceil(100000/128)
#define NBLK    256         // blocks for hist/scatter passes
#define EB      (N_EDGES / NBLK)   // 12500 edges per block
#define COLMASK 0xFFFFF     // col in low 20 bits; row&127 in bits 20..26

// ---------- CSR build: two-level bucket sort (write-locality-friendly) ----------

// per-block histogram over 782 row-buckets
__global__ __launch_bounds__(256) void bucket_hist(const int* __restrict__ er, int* __restrict__ blockCnt) {
    __shared__ int h[NB];
    for (int i = threadIdx.x; i < NB; i += 256) h[i] = 0;
    __syncthreads();
    int base = blockIdx.x * EB;
    for (int e = base + threadIdx.x; e < base + EB; e += 256)
        atomicAdd(&h[er[e] >> 7], 1);
    __syncthreads();
    for (int i = threadIdx.x; i < NB; i += 256) blockCnt[blockIdx.x * NB + i] = h[i];
}

// per-bucket exclusive scan over the 256 block counts
__global__ __launch_bounds__(256) void bucket_scan_a(const int* __restrict__ blockCnt,
                                                     int* __restrict__ blockOff,
                                                     int* __restrict__ bucketTotal) {
    __shared__ int s[256];
    int b = blockIdx.x, t = threadIdx.x;
    int v = blockCnt[t * NB + b];
    s[t] = v; __syncthreads();
    for (int off = 1; off < 256; off <<= 1) {
        int u = (t >= off) ? s[t - off] : 0;
        __syncthreads();
        s[t] += u;
        __syncthreads();
    }
    blockOff[t * NB + b] = s[t] - v;   // exclusive prefix within bucket
    if (t == 255) bucketTotal[b] = s[255];
}

// scan bucket totals -> bucketStart; also rp[N]=E
__global__ __launch_bounds__(1024) void bucket_scan_b(const int* __restrict__ bucketTotal,
                                                      int* __restrict__ bucketStart,
                                                      int* __restrict__ rp, int E) {
    __shared__ int s[1024];
    int t = threadIdx.x;
    int v = (t < NB) ? bucketTotal[t] : 0;
    s[t] = v; __syncthreads();
    for (int off = 1; off < 1024; off <<= 1) {
        int u = (t >= off) ? s[t - off] : 0;
        __syncthreads();
        s[t] += u;
        __syncthreads();
    }
    if (t < NB) bucketStart[t] = s[t] - v;
    if (t == 0) { bucketStart[NB] = E; rp[N_NODES] = E; }
}

// scatter edges into bucket-grouped order; each block writes contiguous slices
__global__ __launch_bounds__(256) void bucket_scatter(const int* __restrict__ er, const int* __restrict__ ec,
                                                      const float* __restrict__ ev,
                                                      const int* __restrict__ blockOff,
                                                      const int* __restrict__ bucketStart,
                                                      int2* __restrict__ cpackT) {
    __shared__ int cur[NB];
    for (int i = threadIdx.x; i < NB; i += 256)
        cur[i] = bucketStart[i] + blockOff[blockIdx.x * NB + i];
    __syncthreads();
    int base = blockIdx.x * EB;
    for (int e = base + threadIdx.x; e < base + EB; e += 256) {
        int r = er[e];
        int p = atomicAdd(&cur[r >> 7], 1);
        cpackT[p] = make_int2(((r & 127) << 20) | ec[e], __float_as_int(ev[e]));
    }
}

// within-bucket sort by row (one block owns one 32KB bucket region) + emit rp
__global__ __launch_bounds__(256) void bucket_sort(const int2* __restrict__ cpackT,
                                                   const int* __restrict__ bucketStart,
                                                   int2* __restrict__ cpack, int* __restrict__ rp) {
    __shared__ int cnt[128];
    __shared__ int cursor[128];
    int b = blockIdx.x, t = threadIdx.x;
    int s = bucketStart[b], e = bucketStart[b + 1];
    if (t < 128) cnt[t] = 0;
    __syncthreads();
    for (int j = s + t; j < e; j += 256)
        atomicAdd(&cnt[cpackT[j].x >> 20], 1);
    __syncthreads();
    int val = (t < 128) ? cnt[t] : 0;
    for (int off = 1; off < 128; off <<= 1) {
        int u = (t < 128 && t >= off) ? cnt[t - off] : 0;
        __syncthreads();
        if (t < 128) cnt[t] += u;
        __syncthreads();
    }
    if (t < 128) {
        int excl = cnt[t] - val;
        cursor[t] = s + excl;
        int gr = b * 128 + t;
        if (gr < N_NODES) rp[gr] = s + excl;
    }
    __syncthreads();
    for (int j = s + t; j < e; j += 256) {
        int2 v = cpackT[j];
        int p = atomicAdd(&cursor[v.x >> 20], 1);
        cpack[p] = v;
    }
}

// ---------- weight transpose + bf16 convert:  W[K][Nc] -> Wt[Nc][K] ----------
__global__ __launch_bounds__(256) void transpose_k(const float* __restrict__ W, unsigned short* __restrict__ Wt,
                                                   int K, int Nc) {
    int i = blockIdx.x * 256 + threadIdx.x;
    if (i < K * Nc) {
        int k = i / Nc, n = i % Nc;
        Wt[(size_t)n * K + k] = f2bf(W[i]);
    }
}

// ---------- MFMA GEMM: C[Mpad][Nc](bf16) = A[Mpad][K] @ Bt[Nc][K]^T ----------
template<int BM, int BN, int BK, bool A_F32>
__global__ __launch_bounds__(256) void gemm_mfma(const void* __restrict__ Aptr,
                                                 const unsigned short* __restrict__ Bt,
                                                 unsigned short* __restrict__ C,
                                                 int K, int Nc, int Mclamp) {
    constexpr int WROWS = 2, WCOLS = 2;
    constexpr int WM = BM / WROWS, WN = BN / WCOLS;
    constexpr int MT = WM / 16, NT = WN / 16;
    constexpr int LDA = BK + 8;
    constexpr int KV = BK / 8;

    __shared__ unsigned short lds_a[BM * LDA];
    __shared__ unsigned short lds_b[BN * LDA];

    const int tid  = threadIdx.x;
    const int wid  = tid >> 6, lane = tid & 63;
    const int wrow = wid >> 1, wcol = wid & 1;
    const int bm = blockIdx.x * BM, bn = blockIdx.y * BN;
    const int r = lane & 15, q = lane >> 4;

    const float*          Af = (const float*)Aptr;
    const unsigned short* Ab = (const unsigned short*)Aptr;

    f32x4 acc[MT][NT];
    f32x4 zero = {0.f, 0.f, 0.f, 0.f};
#pragma unroll
    for (int mi = 0; mi < MT; mi++)
#pragma unroll
        for (int ni = 0; ni < NT; ni++) acc[mi][ni] = zero;

    for (int k0 = 0; k0 < K; k0 += BK) {
#pragma unroll
        for (int it = 0; it < (BM * KV) / 256; it++) {
            int v = tid + it * 256;
            int row = v / KV, kc = (v % KV) * 8;
            int grow = bm + row;
            uint4 d;
            if constexpr (A_F32) {
                grow = (grow <= Mclamp) ? grow : Mclamp;
                const float4* pp = (const float4*)(Af + (size_t)grow * K + k0 + kc);
                float4 f0 = pp[0], f1 = pp[1];
                d.x = (unsigned)f2bf(f0.x) | ((unsigned)f2bf(f0.y) << 16);
                d.y = (unsigned)f2bf(f0.z) | ((unsigned)f2bf(f0.w) << 16);
                d.z = (unsigned)f2bf(f1.x) | ((unsigned)f2bf(f1.y) << 16);
                d.w = (unsigned)f2bf(f1.z) | ((unsigned)f2bf(f1.w) << 16);
            } else {
                d = *(const uint4*)(Ab + (size_t)grow * K + k0 + kc);
            }
            *(uint4*)&lds_a[row * LDA + kc] = d;
        }
#pragma unroll
        for (int it = 0; it < (BN * KV) / 256; it++) {
            int v = tid + it * 256;
            int row = v / KV, kc = (v % KV) * 8;
            uint4 d = *(const uint4*)(Bt + (size_t)(bn + row) * K + k0 + kc);
            *(uint4*)&lds_b[row * LDA + kc] = d;
        }
        __syncthreads();

#pragma unroll
        for (int kk = 0; kk < BK; kk += 32) {
            bf16x8 av[MT], bv[NT];
#pragma unroll
            for (int mi = 0; mi < MT; mi++)
                av[mi] = *(const bf16x8*)&lds_a[(wrow * WM + mi * 16 + r) * LDA + kk + q * 8];
#pragma unroll
            for (int ni = 0; ni < NT; ni++)
                bv[ni] = *(const bf16x8*)&lds_b[(wcol * WN + ni * 16 + r) * LDA + kk + q * 8];
#pragma unroll
            for (int mi = 0; mi < MT; mi++)
#pragma unroll
                for (int ni = 0; ni < NT; ni++)
                    acc[mi][ni] = __builtin_amdgcn_mfma_f32_16x16x32_bf16(av[mi], bv[ni], acc[mi][ni], 0, 0, 0);
        }
        __syncthreads();
    }

#pragma unroll
    for (int mi = 0; mi < MT; mi++) {
        int row = bm + wrow * WM + mi * 16 + q * 4;
#pragma unroll
        for (int ni = 0; ni < NT; ni++) {
            int cc = bn + wcol * WN + ni * 16 + r;
#pragma unroll
            for (int d = 0; d < 4; d++)
                C[(size_t)(row + d) * Nc + cc] = f2bf(acc[mi][ni][d]);
        }
    }
}

// ---------- SPMM (F=256): one wave per row, lane owns 4 features ----------
__global__ __launch_bounds__(256) void spmm_f256(const int* __restrict__ rp, const int2* __restrict__ cpack,
                                                 const unsigned short* __restrict__ Z,
                                                 const float* __restrict__ bias, unsigned short* __restrict__ H, int N) {
    int w = (blockIdx.x * 256 + threadIdx.x) >> 6;
    if (w >= N) return;
    int lane = threadIdx.x & 63;
    int f0 = lane * 4;
    int s = rp[w], e = rp[w + 1];
    float a0 = 0.f, a1 = 0.f, a2 = 0.f, a3 = 0.f;
    int j = s;
    for (; j + 4 <= e; j += 4) {
        int2 e0 = cpack[j], e1 = cpack[j + 1], e2 = cpack[j + 2], e3 = cpack[j + 3];
        ushort4 z0 = *(const ushort4*)(Z + (size_t)(e0.x & COLMASK) * 256 + f0);
        ushort4 z1 = *(const ushort4*)(Z + (size_t)(e1.x & COLMASK) * 256 + f0);
        ushort4 z2 = *(const ushort4*)(Z + (size_t)(e2.x & COLMASK) * 256 + f0);
        ushort4 z3 = *(const ushort4*)(Z + (size_t)(e3.x & COLMASK) * 256 + f0);
        float w0 = __int_as_float(e0.y), w1 = __int_as_float(e1.y);
        float w2 = __int_as_float(e2.y), w3 = __int_as_float(e3.y);
        a0 += w0 * bf2f(z0.x); a1 += w0 * bf2f(z0.y); a2 += w0 * bf2f(z0.z); a3 += w0 * bf2f(z0.w);
        a0 += w1 * bf2f(z1.x); a1 += w1 * bf2f(z1.y); a2 += w1 * bf2f(z1.z); a3 += w1 * bf2f(z1.w);
        a0 += w2 * bf2f(z2.x); a1 += w2 * bf2f(z2.y); a2 += w2 * bf2f(z2.z); a3 += w2 * bf2f(z2.w);
        a0 += w3 * bf2f(z3.x); a1 += w3 * bf2f(z3.y); a2 += w3 * bf2f(z3.z); a3 += w3 * bf2f(z3.w);
    }
    for (; j < e; j++) {
        int2 e0 = cpack[j];
        float w0 = __int_as_float(e0.y);
        ushort4 z0 = *(const ushort4*)(Z + (size_t)(e0.x & COLMASK) * 256 + f0);
        a0 += w0 * bf2f(z0.x); a1 += w0 * bf2f(z0.y); a2 += w0 * bf2f(z0.z); a3 += w0 * bf2f(z0.w);
    }
    float4 b = *(const float4*)(bias + f0);
    a0 = fmaxf(a0 + b.x, 0.f); a1 = fmaxf(a1 + b.y, 0.f);
    a2 = fmaxf(a2 + b.z, 0.f); a3 = fmaxf(a3 + b.w, 0.f);
    ushort4 o; o.x = f2bf(a0); o.y = f2bf(a1); o.z = f2bf(a2); o.w = f2bf(a3);
    *(ushort4*)(H + (size_t)w * 256 + f0) = o;
}

// ---------- SPMM (F=64) + bias + log_softmax fused ----------
__global__ __launch_bounds__(256) void spmm_f64_lsm(const int* __restrict__ rp, const int2* __restrict__ cpack,
                                                    const unsigned short* __restrict__ Z,
                                                    const float* __restrict__ bias, float* __restrict__ out, int N) {
    int w = (blockIdx.x * 256 + threadIdx.x) >> 6;
    if (w >= N) return;
    int lane = threadIdx.x & 63;
    int s = rp[w], e = rp[w + 1];
    float a = 0.f;
    int j = s;
    for (; j + 4 <= e; j += 4) {
        int2 e0 = cpack[j], e1 = cpack[j + 1], e2 = cpack[j + 2], e3 = cpack[j + 3];
        float z0 = bf2f(Z[(size_t)(e0.x & COLMASK) * 64 + lane]);
        float z1 = bf2f(Z[(size_t)(e1.x & COLMASK) * 64 + lane]);
        float z2 = bf2f(Z[(size_t)(e2.x & COLMASK) * 64 + lane]);
        float z3 = bf2f(Z[(size_t)(e3.x & COLMASK) * 64 + lane]);
        a += __int_as_float(e0.y) * z0 + __int_as_float(e1.y) * z1;
        a += __int_as_float(e2.y) * z2 + __int_as_float(e3.y) * z3;
    }
    for (; j < e; j++) {
        int2 e0 = cpack[j];
        a += __int_as_float(e0.y) * bf2f(Z[(size_t)(e0.x & COLMASK) * 64 + lane]);
    }
    a += bias[lane];
    float m = a;
    for (int off = 32; off >= 1; off >>= 1) m = fmaxf(m, __shfl_xor(m, off, 64));
    float ex = __expf(a - m);
    float sum = ex;
    for (int off = 32; off >= 1; off >>= 1) sum += __shfl_xor(sum, off, 64);
    out[(size_t)w * 64 + lane] = a - m - __logf(sum);
}

// ---------- launch ----------
extern "C" void kernel_launch(void* const* d_in, const int* in_sizes, int n_in,
                              void* d_out, int out_size, void* d_ws, size_t ws_size,
                              hipStream_t stream) {
    const float* x  = (const float*)d_in[0];
    const int*   er = (const int*)  d_in[1];
    const int*   ec = (const int*)  d_in[2];
    const float* ev = (const float*)d_in[3];
    const float* W1 = (const float*)d_in[4];
    const float* b1 = (const float*)d_in[5];
    const float* W2 = (const float*)d_in[6];
    const float* b2 = (const float*)d_in[7];
    const float* W3 = (const float*)d_in[8];
    const float* b3 = (const float*)d_in[9];

    const int N = N_NODES, E = N_EDGES;

    char* p = (char*)d_ws;
    auto alloc = [&](size_t bytes) -> char* {
        char* q = p; p += (bytes + 255) & ~(size_t)255; return q;
    };
    unsigned short* Wt1    = (unsigned short*)alloc((size_t)256 * 512 * 2);
    unsigned short* Wt2    = (unsigned short*)alloc((size_t)256 * 256 * 2);
    unsigned short* Wt3    = (unsigned short*)alloc((size_t)64  * 256 * 2);
    int*            rp     = (int*)  alloc((size_t)(N + 1) * 4);
    int*            blkCnt = (int*)  alloc((size_t)NBLK * NB * 4);
    int*            blkOff = (int*)  alloc((size_t)NBLK * NB * 4);
    int*            bktTot = (int*)  alloc((size_t)NB * 4);
    int*            bktSt  = (int*)  alloc((size_t)(NB + 1) * 4);
    int2*           cpack  = (int2*) alloc((size_t)E * 8);
    unsigned short* bufA   = (unsigned short*)alloc((size_t)MPAD * 256 * 2);
    unsigned short* bufB   = (unsigned short*)alloc((size_t)MPAD * 256 * 2);
    int2*           cpackT = (int2*)bufA;   // overlay: bufA unused until gemm1

    // CSR build (bucketed two-level sort; no global atomics on HBM-resident data)
    bucket_hist   <<<NBLK, 256, 0, stream>>>(er, blkCnt);
    bucket_scan_a <<<NB,   256, 0, stream>>>(blkCnt, blkOff, bktTot);
    bucket_scan_b <<<1,   1024, 0, stream>>>(bktTot, bktSt, rp, E);
    bucket_scatter<<<NBLK, 256, 0, stream>>>(er, ec, ev, blkOff, bktSt, cpackT);
    bucket_sort   <<<NB,   256, 0, stream>>>(cpackT, bktSt, cpack, rp);

    // weights -> bf16 transposed
    transpose_k<<<(512 * 256) / 256, 256, 0, stream>>>(W1, Wt1, 512, 256);
    transpose_k<<<(256 * 256) / 256, 256, 0, stream>>>(W2, Wt2, 256, 256);
    transpose_k<<<(256 * 64)  / 256, 256, 0, stream>>>(W3, Wt3, 256, 64);

    // layer 1: Z = x @ W1 ; H = relu(spmm(Z) + b1)
    gemm_mfma<64, 256, 64, true ><<<dim3(MPAD / 64, 1), 256, 0, stream>>>(x,    Wt1, bufA, 512, 256, N - 1);
    spmm_f256<<<N / 4, 256, 0, stream>>>(rp, cpack, bufA, b1, bufB, N);
    // layer 2
    gemm_mfma<64, 256, 64, false><<<dim3(MPAD / 64, 1), 256, 0, stream>>>(bufB, Wt2, bufA, 256, 256, N - 1);
    spmm_f256<<<N / 4, 256, 0, stream>>>(rp, cpack, bufA, b2, bufB, N);
    // layer 3 (+ fused bias + log_softmax)
    gemm_mfma<128, 64, 64, false><<<dim3(MPAD / 128, 1), 256, 0, stream>>>(bufB, Wt3, bufA, 256, 64, N - 1);
    spmm_f64_lsm<<<N / 4, 256, 0, stream>>>(rp, cpack, bufA, b3, (float*)d_out, N);
}

// Round 4
// 1041.181 us; speedup vs baseline: 1.4458x; 1.0167x over previous
//
#include <hip/hip_runtime.h>
#include <stdint.h>
#include <stddef.h>

// ---------- types & helpers ----------
typedef __bf16 bf16x8 __attribute__((ext_vector_type(8)));
typedef float  f32x4  __attribute__((ext_vector_type(4)));

static __device__ __forceinline__ float bf2f(unsigned short u) {
    union { unsigned int i; float f; } v; v.i = ((unsigned int)u) << 16; return v.f;
}
static __device__ __forceinline__ unsigned short f2bf(float f) {
    union { float f; unsigned int i; } v; v.f = f;
    unsigned int r = v.i + 0x7FFFu + ((v.i >> 16) & 1u);
    return (unsigned short)(r >> 16);
}

#define N_NODES 100000
#define N_EDGES 3200000
#define MPAD    100096      // multiple of 128
#define NB      782         // buckets of 128 rows: ceil(100000/128)
#define NBLK    256         // blocks for hist/scatter passes
#define EB      (N_EDGES / NBLK)   // 12500 edges per block
#define COLMASK 0xFFFFF     // col in low 20 bits; row&127 in bits 20..26

// ---------- CSR build: two-level bucket sort (write-locality-friendly) ----------

__global__ __launch_bounds__(256) void bucket_hist(const int* __restrict__ er, int* __restrict__ blockCnt) {
    __shared__ int h[NB];
    for (int i = threadIdx.x; i < NB; i += 256) h[i] = 0;
    __syncthreads();
    int base = blockIdx.x * EB;
    for (int e = base + threadIdx.x; e < base + EB; e += 256)
        atomicAdd(&h[er[e] >> 7], 1);
    __syncthreads();
    for (int i = threadIdx.x; i < NB; i += 256) blockCnt[blockIdx.x * NB + i] = h[i];
}

__global__ __launch_bounds__(256) void bucket_scan_a(const int* __restrict__ blockCnt,
                                                     int* __restrict__ blockOff,
                                                     int* __restrict__ bucketTotal) {
    __shared__ int s[256];
    int b = blockIdx.x, t = threadIdx.x;
    int v = blockCnt[t * NB + b];
    s[t] = v; __syncthreads();
    for (int off = 1; off < 256; off <<= 1) {
        int u = (t >= off) ? s[t - off] : 0;
        __syncthreads();
        s[t] += u;
        __syncthreads();
    }
    blockOff[t * NB + b] = s[t] - v;
    if (t == 255) bucketTotal[b] = s[255];
}

__global__ __launch_bounds__(1024) void bucket_scan_b(const int* __restrict__ bucketTotal,
                                                      int* __restrict__ bucketStart,
                                                      int* __restrict__ rp, int E) {
    __shared__ int s[1024];
    int t = threadIdx.x;
    int v = (t < NB) ? bucketTotal[t] : 0;
    s[t] = v; __syncthreads();
    for (int off = 1; off < 1024; off <<= 1) {
        int u = (t >= off) ? s[t - off] : 0;
        __syncthreads();
        s[t] += u;
        __syncthreads();
    }
    if (t < NB) bucketStart[t] = s[t] - v;
    if (t == 0) { bucketStart[NB] = E; rp[N_NODES] = E; }
}

__global__ __launch_bounds__(256) void bucket_scatter(const int* __restrict__ er, const int* __restrict__ ec,
                                                      const float* __restrict__ ev,
                                                      const int* __restrict__ blockOff,
                                                      const int* __restrict__ bucketStart,
                                                      int2* __restrict__ cpackT) {
    __shared__ int cur[NB];
    for (int i = threadIdx.x; i < NB; i += 256)
        cur[i] = bucketStart[i] + blockOff[blockIdx.x * NB + i];
    __syncthreads();
    int base = blockIdx.x * EB;
    for (int e = base + threadIdx.x; e < base + EB; e += 256) {
        int r = er[e];
        int p = atomicAdd(&cur[r >> 7], 1);
        cpackT[p] = make_int2(((r & 127) << 20) | ec[e], __float_as_int(ev[e]));
    }
}

__global__ __launch_bounds__(256) void bucket_sort(const int2* __restrict__ cpackT,
                                                   const int* __restrict__ bucketStart,
                                                   int2* __restrict__ cpack, int* __restrict__ rp) {
    __shared__ int cnt[128];
    __shared__ int cursor[128];
    int b = blockIdx.x, t = threadIdx.x;
    int s = bucketStart[b], e = bucketStart[b + 1];
    if (t < 128) cnt[t] = 0;
    __syncthreads();
    for (int j = s + t; j < e; j += 256)
        atomicAdd(&cnt[cpackT[j].x >> 20], 1);
    __syncthreads();
    int val = (t < 128) ? cnt[t] : 0;
    for (int off = 1; off < 128; off <<= 1) {
        int u = (t < 128 && t >= off) ? cnt[t - off] : 0;
        __syncthreads();
        if (t < 128) cnt[t] += u;
        __syncthreads();
    }
    if (t < 128) {
        int excl = cnt[t] - val;
        cursor[t] = s + excl;
        int gr = b * 128 + t;
        if (gr < N_NODES) rp[gr] = s + excl;
    }
    __syncthreads();
    for (int j = s + t; j < e; j += 256) {
        int2 v = cpackT[j];
        int p = atomicAdd(&cursor[v.x >> 20], 1);
        cpack[p] = v;
    }
}

// ---------- weight transpose + bf16 convert ----------
__global__ __launch_bounds__(256) void transpose_k(const float* __restrict__ W, unsigned short* __restrict__ Wt,
                                                   int K, int Nc) {
    int i = blockIdx.x * 256 + threadIdx.x;
    if (i < K * Nc) {
        int k = i / Nc, n = i % Nc;
        Wt[(size_t)n * K + k] = f2bf(W[i]);
    }
}

// ---------- MFMA GEMM ----------
template<int BM, int BN, int BK, bool A_F32>
__global__ __launch_bounds__(256) void gemm_mfma(const void* __restrict__ Aptr,
                                                 const unsigned short* __restrict__ Bt,
                                                 unsigned short* __restrict__ C,
                                                 int K, int Nc, int Mclamp) {
    constexpr int WROWS = 2, WCOLS = 2;
    constexpr int WM = BM / WROWS, WN = BN / WCOLS;
    constexpr int MT = WM / 16, NT = WN / 16;
    constexpr int LDA = BK + 8;
    constexpr int KV = BK / 8;

    __shared__ unsigned short lds_a[BM * LDA];
    __shared__ unsigned short lds_b[BN * LDA];

    const int tid  = threadIdx.x;
    const int wid  = tid >> 6, lane = tid & 63;
    const int wrow = wid >> 1, wcol = wid & 1;
    const int bm = blockIdx.x * BM, bn = blockIdx.y * BN;
    const int r = lane & 15, q = lane >> 4;

    const float*          Af = (const float*)Aptr;
    const unsigned short* Ab = (const unsigned short*)Aptr;

    f32x4 acc[MT][NT];
    f32x4 zero = {0.f, 0.f, 0.f, 0.f};
#pragma unroll
    for (int mi = 0; mi < MT; mi++)
#pragma unroll
        for (int ni = 0; ni < NT; ni++) acc[mi][ni] = zero;

    for (int k0 = 0; k0 < K; k0 += BK) {
#pragma unroll
        for (int it = 0; it < (BM * KV) / 256; it++) {
            int v = tid + it * 256;
            int row = v / KV, kc = (v % KV) * 8;
            int grow = bm + row;
            uint4 d;
            if constexpr (A_F32) {
                grow = (grow <= Mclamp) ? grow : Mclamp;
                const float4* pp = (const float4*)(Af + (size_t)grow * K + k0 + kc);
                float4 f0 = pp[0], f1 = pp[1];
                d.x = (unsigned)f2bf(f0.x) | ((unsigned)f2bf(f0.y) << 16);
                d.y = (unsigned)f2bf(f0.z) | ((unsigned)f2bf(f0.w) << 16);
                d.z = (unsigned)f2bf(f1.x) | ((unsigned)f2bf(f1.y) << 16);
                d.w = (unsigned)f2bf(f1.z) | ((unsigned)f2bf(f1.w) << 16);
            } else {
                d = *(const uint4*)(Ab + (size_t)grow * K + k0 + kc);
            }
            *(uint4*)&lds_a[row * LDA + kc] = d;
        }
#pragma unroll
        for (int it = 0; it < (BN * KV) / 256; it++) {
            int v = tid + it * 256;
            int row = v / KV, kc = (v % KV) * 8;
            uint4 d = *(const uint4*)(Bt + (size_t)(bn + row) * K + k0 + kc);
            *(uint4*)&lds_b[row * LDA + kc] = d;
        }
        __syncthreads();

#pragma unroll
        for (int kk = 0; kk < BK; kk += 32) {
            bf16x8 av[MT], bv[NT];
#pragma unroll
            for (int mi = 0; mi < MT; mi++)
                av[mi] = *(const bf16x8*)&lds_a[(wrow * WM + mi * 16 + r) * LDA + kk + q * 8];
#pragma unroll
            for (int ni = 0; ni < NT; ni++)
                bv[ni] = *(const bf16x8*)&lds_b[(wcol * WN + ni * 16 + r) * LDA + kk + q * 8];
#pragma unroll
            for (int mi = 0; mi < MT; mi++)
#pragma unroll
                for (int ni = 0; ni < NT; ni++)
                    acc[mi][ni] = __builtin_amdgcn_mfma_f32_16x16x32_bf16(av[mi], bv[ni], acc[mi][ni], 0, 0, 0);
        }
        __syncthreads();
    }

#pragma unroll
    for (int mi = 0; mi < MT; mi++) {
        int row = bm + wrow * WM + mi * 16 + q * 4;
#pragma unroll
        for (int ni = 0; ni < NT; ni++) {
            int cc = bn + wcol * WN + ni * 16 + r;
#pragma unroll
            for (int d = 0; d < 4; d++)
                C[(size_t)(row + d) * Nc + cc] = f2bf(acc[mi][ni][d]);
        }
    }
}

// ---------- SPMM (F=256): wave per row, 8 gathers in flight, predicated tail ----------
__global__ __launch_bounds__(256) void spmm_f256(const int* __restrict__ rp, const int2* __restrict__ cpack,
                                                 const unsigned short* __restrict__ Z,
                                                 const float* __restrict__ bias, unsigned short* __restrict__ H, int N) {
    int w = (blockIdx.x * 256 + threadIdx.x) >> 6;
    if (w >= N) return;
    int lane = threadIdx.x & 63;
    int f0 = lane * 4;
    int s = rp[w], e = rp[w + 1];
    float a0 = 0.f, a1 = 0.f, a2 = 0.f, a3 = 0.f;
    int j = s;
    for (; j + 8 <= e; j += 8) {
        const int4* ep = (const int4*)(cpack + j);
        int4 p0 = ep[0], p1 = ep[1], p2 = ep[2], p3 = ep[3];
        ushort4 z0 = *(const ushort4*)(Z + (size_t)(p0.x & COLMASK) * 256 + f0);
        ushort4 z1 = *(const ushort4*)(Z + (size_t)(p0.z & COLMASK) * 256 + f0);
        ushort4 z2 = *(const ushort4*)(Z + (size_t)(p1.x & COLMASK) * 256 + f0);
        ushort4 z3 = *(const ushort4*)(Z + (size_t)(p1.z & COLMASK) * 256 + f0);
        ushort4 z4 = *(const ushort4*)(Z + (size_t)(p2.x & COLMASK) * 256 + f0);
        ushort4 z5 = *(const ushort4*)(Z + (size_t)(p2.z & COLMASK) * 256 + f0);
        ushort4 z6 = *(const ushort4*)(Z + (size_t)(p3.x & COLMASK) * 256 + f0);
        ushort4 z7 = *(const ushort4*)(Z + (size_t)(p3.z & COLMASK) * 256 + f0);
        float w0 = __int_as_float(p0.y), w1 = __int_as_float(p0.w);
        float w2 = __int_as_float(p1.y), w3 = __int_as_float(p1.w);
        float w4 = __int_as_float(p2.y), w5 = __int_as_float(p2.w);
        float w6 = __int_as_float(p3.y), w7 = __int_as_float(p3.w);
        a0 += w0 * bf2f(z0.x); a1 += w0 * bf2f(z0.y); a2 += w0 * bf2f(z0.z); a3 += w0 * bf2f(z0.w);
        a0 += w1 * bf2f(z1.x); a1 += w1 * bf2f(z1.y); a2 += w1 * bf2f(z1.z); a3 += w1 * bf2f(z1.w);
        a0 += w2 * bf2f(z2.x); a1 += w2 * bf2f(z2.y); a2 += w2 * bf2f(z2.z); a3 += w2 * bf2f(z2.w);
        a0 += w3 * bf2f(z3.x); a1 += w3 * bf2f(z3.y); a2 += w3 * bf2f(z3.z); a3 += w3 * bf2f(z3.w);
        a0 += w4 * bf2f(z4.x); a1 += w4 * bf2f(z4.y); a2 += w4 * bf2f(z4.z); a3 += w4 * bf2f(z4.w);
        a0 += w5 * bf2f(z5.x); a1 += w5 * bf2f(z5.y); a2 += w5 * bf2f(z5.z); a3 += w5 * bf2f(z5.w);
        a0 += w6 * bf2f(z6.x); a1 += w6 * bf2f(z6.y); a2 += w6 * bf2f(z6.z); a3 += w6 * bf2f(z6.w);
        a0 += w7 * bf2f(z7.x); a1 += w7 * bf2f(z7.y); a2 += w7 * bf2f(z7.z); a3 += w7 * bf2f(z7.w);
    }
    if (j < e) {
        // predicated 8-wide tail: invalid slots -> col 0, weight 0
#pragma unroll
        for (int t = 0; t < 8; t++) {
            int jj = j + t;
            int2 ed = (jj < e) ? cpack[jj] : make_int2(0, 0);
            float wt = __int_as_float(ed.y);
            ushort4 z = *(const ushort4*)(Z + (size_t)(ed.x & COLMASK) * 256 + f0);
            a0 += wt * bf2f(z.x); a1 += wt * bf2f(z.y); a2 += wt * bf2f(z.z); a3 += wt * bf2f(z.w);
        }
    }
    float4 b = *(const float4*)(bias + f0);
    a0 = fmaxf(a0 + b.x, 0.f); a1 = fmaxf(a1 + b.y, 0.f);
    a2 = fmaxf(a2 + b.z, 0.f); a3 = fmaxf(a3 + b.w, 0.f);
    ushort4 o; o.x = f2bf(a0); o.y = f2bf(a1); o.z = f2bf(a2); o.w = f2bf(a3);
    *(ushort4*)(H + (size_t)w * 256 + f0) = o;
}

// ---------- SPMM (F=64) + bias + log_softmax: 4 edges per gather instruction ----------
// lane = (g, fl): g = lane>>4 edge subgroup, fl = lane&15 feature quad
__global__ __launch_bounds__(256) void spmm_f64_lsm(const int* __restrict__ rp, const int2* __restrict__ cpack,
                                                    const unsigned short* __restrict__ Z,
                                                    const float* __restrict__ bias, float* __restrict__ out, int N) {
    int w = (blockIdx.x * 256 + threadIdx.x) >> 6;
    if (w >= N) return;
    int lane = threadIdx.x & 63;
    int g = lane >> 4, fl = lane & 15;
    int s = rp[w], e = rp[w + 1];
    float a0 = 0.f, a1 = 0.f, a2 = 0.f, a3 = 0.f;
    for (int j = s; j < e; j += 8) {
        int j0 = j + g, j1 = j + 4 + g;
        int2 e0 = (j0 < e) ? cpack[j0] : make_int2(0, 0);
        int2 e1 = (j1 < e) ? cpack[j1] : make_int2(0, 0);
        ushort4 z0 = *(const ushort4*)(Z + (size_t)(e0.x & COLMASK) * 64 + fl * 4);
        ushort4 z1 = *(const ushort4*)(Z + (size_t)(e1.x & COLMASK) * 64 + fl * 4);
        float w0 = __int_as_float(e0.y), w1 = __int_as_float(e1.y);
        a0 += w0 * bf2f(z0.x); a1 += w0 * bf2f(z0.y); a2 += w0 * bf2f(z0.z); a3 += w0 * bf2f(z0.w);
        a0 += w1 * bf2f(z1.x); a1 += w1 * bf2f(z1.y); a2 += w1 * bf2f(z1.z); a3 += w1 * bf2f(z1.w);
    }
    // combine the 4 edge subgroups (lanes differing in bits 4..5)
    a0 += __shfl_xor(a0, 16, 64); a1 += __shfl_xor(a1, 16, 64);
    a2 += __shfl_xor(a2, 16, 64); a3 += __shfl_xor(a3, 16, 64);
    a0 += __shfl_xor(a0, 32, 64); a1 += __shfl_xor(a1, 32, 64);
    a2 += __shfl_xor(a2, 32, 64); a3 += __shfl_xor(a3, 32, 64);
    float4 b = *(const float4*)(bias + fl * 4);
    a0 += b.x; a1 += b.y; a2 += b.z; a3 += b.w;
    // log_softmax over 64 feats (held as 4 per lane across 16 fl lanes, replicated over g)
    float m = fmaxf(fmaxf(a0, a1), fmaxf(a2, a3));
    for (int off = 1; off <= 8; off <<= 1) m = fmaxf(m, __shfl_xor(m, off, 64));
    float sum = __expf(a0 - m) + __expf(a1 - m) + __expf(a2 - m) + __expf(a3 - m);
    for (int off = 1; off <= 8; off <<= 1) sum += __shfl_xor(sum, off, 64);
    float lse = m + __logf(sum);
    if (g == 0) {
        float4 o = make_float4(a0 - lse, a1 - lse, a2 - lse, a3 - lse);
        *(float4*)(out + (size_t)w * 64 + fl * 4) = o;
    }
}

// ---------- launch ----------
extern "C" void kernel_launch(void* const* d_in, const int* in_sizes, int n_in,
                              void* d_out, int out_size, void* d_ws, size_t ws_size,
                              hipStream_t stream) {
    const float* x  = (const float*)d_in[0];
    const int*   er = (const int*)  d_in[1];
    const int*   ec = (const int*)  d_in[2];
    const float* ev = (const float*)d_in[3];
    const float* W1 = (const float*)d_in[4];
    const float* b1 = (const float*)d_in[5];
    const float* W2 = (const float*)d_in[6];
    const float* b2 = (const float*)d_in[7];
    const float* W3 = (const float*)d_in[8];
    const float* b3 = (const float*)d_in[9];

    const int N = N_NODES, E = N_EDGES;

    char* p = (char*)d_ws;
    auto alloc = [&](size_t bytes) -> char* {
        char* q = p; p += (bytes + 255) & ~(size_t)255; return q;
    };
    unsigned short* Wt1    = (unsigned short*)alloc((size_t)256 * 512 * 2);
    unsigned short* Wt2    = (unsigned short*)alloc((size_t)256 * 256 * 2);
    unsigned short* Wt3    = (unsigned short*)alloc((size_t)64  * 256 * 2);
    int*            rp     = (int*)  alloc((size_t)(N + 1) * 4);
    int*            blkCnt = (int*)  alloc((size_t)NBLK * NB * 4);
    int*            blkOff = (int*)  alloc((size_t)NBLK * NB * 4);
    int*            bktTot = (int*)  alloc((size_t)NB * 4);
    int*            bktSt  = (int*)  alloc((size_t)(NB + 1) * 4);
    int2*           cpack  = (int2*) alloc((size_t)E * 8);
    unsigned short* bufA   = (unsigned short*)alloc((size_t)MPAD * 256 * 2);
    unsigned short* bufB   = (unsigned short*)alloc((size_t)MPAD * 256 * 2);
    int2*           cpackT = (int2*)bufA;   // overlay: bufA unused until gemm1

    // CSR build
    bucket_hist   <<<NBLK, 256, 0, stream>>>(er, blkCnt);
    bucket_scan_a <<<NB,   256, 0, stream>>>(blkCnt, blkOff, bktTot);
    bucket_scan_b <<<1,   1024, 0, stream>>>(bktTot, bktSt, rp, E);
    bucket_scatter<<<NBLK, 256, 0, stream>>>(er, ec, ev, blkOff, bktSt, cpackT);
    bucket_sort   <<<NB,   256, 0, stream>>>(cpackT, bktSt, cpack, rp);

    // weights -> bf16 transposed
    transpose_k<<<(512 * 256) / 256, 256, 0, stream>>>(W1, Wt1, 512, 256);
    transpose_k<<<(256 * 256) / 256, 256, 0, stream>>>(W2, Wt2, 256, 256);
    transpose_k<<<(256 * 64)  / 256, 256, 0, stream>>>(W3, Wt3, 256, 64);

    // layer 1
    gemm_mfma<64, 256, 64, true ><<<dim3(MPAD / 64, 1), 256, 0, stream>>>(x,    Wt1, bufA, 512, 256, N - 1);
    spmm_f256<<<N / 4, 256, 0, stream>>>(rp, cpack, bufA, b1, bufB, N);
    // layer 2
    gemm_mfma<64, 256, 64, false><<<dim3(MPAD / 64, 1), 256, 0, stream>>>(bufB, Wt2, bufA, 256, 256, N - 1);
    spmm_f256<<<N / 4, 256, 0, stream>>>(rp, cpack, bufA, b2, bufB, N);
    // layer 3 (+ fused bias + log_softmax)
    gemm_mfma<128, 64, 64, false><<<dim3(MPAD / 128, 1), 256, 0, stream>>>(bufB, Wt3, bufA, 256, 64, N - 1);
    spmm_f64_lsm<<<N / 4, 256, 0, stream>>>(rp, cpack, bufA, b3, (float*)d_out, N);
}

// Round 5
// 834.494 us; speedup vs baseline: 1.8039x; 1.2477x over previous
//
#include <hip/hip_runtime.h>
#include <stdint.h>
#include <stddef.h>

// ---------- types & helpers ----------
typedef __bf16 bf16x8 __attribute__((ext_vector_type(8)));
typedef float  f32x4  __attribute__((ext_vector_type(4)));
typedef float  f32x2  __attribute__((ext_vector_type(2)));

static __device__ __forceinline__ float bf2f(unsigned short u) {
    union { unsigned int i; float f; } v; v.i = ((unsigned int)u) << 16; return v.f;
}
static __device__ __forceinline__ unsigned short f2bf(float f) {
    union { float f; unsigned int i; } v; v.f = f;
    unsigned int r = v.i + 0x7FFFu + ((v.i >> 16) & 1u);
    return (unsigned short)(r >> 16);
}
// fp8 e4m3 (OCP on gfx950) encode/decode via HW cvt
static __device__ __forceinline__ unsigned char f2fp8(float f) {
    return (unsigned char)(__builtin_amdgcn_cvt_pk_fp8_f32(f, f, 0, false) & 0xFF);
}

#define N_NODES 100000
#define N_EDGES 3200000
#define MPAD    100096      // multiple of 128
#define NB      782         // buckets of 128 rows: ceil(100000/128)
#define NBLK    256         // blocks for hist/scatter passes
#define EB      (N_EDGES / NBLK)   // 12500 edges per block
#define COLMASK 0xFFFFF     // col in low 20 bits; row&127 in bits 20..26

// ---------- CSR build: two-level bucket sort (write-locality-friendly) ----------

__global__ __launch_bounds__(256) void bucket_hist(const int* __restrict__ er, int* __restrict__ blockCnt) {
    __shared__ int h[NB];
    for (int i = threadIdx.x; i < NB; i += 256) h[i] = 0;
    __syncthreads();
    int base = blockIdx.x * EB;
    for (int e = base + threadIdx.x; e < base + EB; e += 256)
        atomicAdd(&h[er[e] >> 7], 1);
    __syncthreads();
    for (int i = threadIdx.x; i < NB; i += 256) blockCnt[blockIdx.x * NB + i] = h[i];
}

__global__ __launch_bounds__(256) void bucket_scan_a(const int* __restrict__ blockCnt,
                                                     int* __restrict__ blockOff,
                                                     int* __restrict__ bucketTotal) {
    __shared__ int s[256];
    int b = blockIdx.x, t = threadIdx.x;
    int v = blockCnt[t * NB + b];
    s[t] = v; __syncthreads();
    for (int off = 1; off < 256; off <<= 1) {
        int u = (t >= off) ? s[t - off] : 0;
        __syncthreads();
        s[t] += u;
        __syncthreads();
    }
    blockOff[t * NB + b] = s[t] - v;
    if (t == 255) bucketTotal[b] = s[255];
}

__global__ __launch_bounds__(1024) void bucket_scan_b(const int* __restrict__ bucketTotal,
                                                      int* __restrict__ bucketStart,
                                                      int* __restrict__ rp, int E) {
    __shared__ int s[1024];
    int t = threadIdx.x;
    int v = (t < NB) ? bucketTotal[t] : 0;
    s[t] = v; __syncthreads();
    for (int off = 1; off < 1024; off <<= 1) {
        int u = (t >= off) ? s[t - off] : 0;
        __syncthreads();
        s[t] += u;
        __syncthreads();
    }
    if (t < NB) bucketStart[t] = s[t] - v;
    if (t == 0) { bucketStart[NB] = E; rp[N_NODES] = E; }
}

__global__ __launch_bounds__(256) void bucket_scatter(const int* __restrict__ er, const int* __restrict__ ec,
                                                      const float* __restrict__ ev,
                                                      const int* __restrict__ blockOff,
                                                      const int* __restrict__ bucketStart,
                                                      int2* __restrict__ cpackT) {
    __shared__ int cur[NB];
    for (int i = threadIdx.x; i < NB; i += 256)
        cur[i] = bucketStart[i] + blockOff[blockIdx.x * NB + i];
    __syncthreads();
    int base = blockIdx.x * EB;
    for (int e = base + threadIdx.x; e < base + EB; e += 256) {
        int r = er[e];
        int p = atomicAdd(&cur[r >> 7], 1);
        cpackT[p] = make_int2(((r & 127) << 20) | ec[e], __float_as_int(ev[e]));
    }
}

__global__ __launch_bounds__(256) void bucket_sort(const int2* __restrict__ cpackT,
                                                   const int* __restrict__ bucketStart,
                                                   int2* __restrict__ cpack, int* __restrict__ rp) {
    __shared__ int cnt[128];
    __shared__ int cursor[128];
    int b = blockIdx.x, t = threadIdx.x;
    int s = bucketStart[b], e = bucketStart[b + 1];
    if (t < 128) cnt[t] = 0;
    __syncthreads();
    for (int j = s + t; j < e; j += 256)
        atomicAdd(&cnt[cpackT[j].x >> 20], 1);
    __syncthreads();
    int val = (t < 128) ? cnt[t] : 0;
    for (int off = 1; off < 128; off <<= 1) {
        int u = (t < 128 && t >= off) ? cnt[t - off] : 0;
        __syncthreads();
        if (t < 128) cnt[t] += u;
        __syncthreads();
    }
    if (t < 128) {
        int excl = cnt[t] - val;
        cursor[t] = s + excl;
        int gr = b * 128 + t;
        if (gr < N_NODES) rp[gr] = s + excl;
    }
    __syncthreads();
    for (int j = s + t; j < e; j += 256) {
        int2 v = cpackT[j];
        int p = atomicAdd(&cursor[v.x >> 20], 1);
        cpack[p] = v;
    }
}

// ---------- fused weight transpose + bf16 convert (all 3 weights, one launch) ----------
// W[K][Nc] -> Wt[Nc][K]
__global__ __launch_bounds__(256) void transpose_all(const float* __restrict__ W1, unsigned short* __restrict__ Wt1,
                                                     const float* __restrict__ W2, unsigned short* __restrict__ Wt2,
                                                     const float* __restrict__ W3, unsigned short* __restrict__ Wt3) {
    int i = blockIdx.x * 256 + threadIdx.x;
    const int S1 = 512 * 256, S2 = 256 * 256, S3 = 256 * 64;
    if (i < S1) {
        int k = i / 256, n = i % 256;
        Wt1[(size_t)n * 512 + k] = f2bf(W1[i]);
    } else if (i < S1 + S2) {
        int j = i - S1; int k = j / 256, n = j % 256;
        Wt2[(size_t)n * 256 + k] = f2bf(W2[j]);
    } else if (i < S1 + S2 + S3) {
        int j = i - S1 - S2; int k = j / 64, n = j % 64;
        Wt3[(size_t)n * 256 + k] = f2bf(W3[j]);
    }
}

// ---------- MFMA GEMM: C = A[Mpad][K] @ Bt[Nc][K]^T ; OUT: 0=bf16, 1=fp8 ----------
template<int BM, int BN, int BK, bool A_F32, int OUT>
__global__ __launch_bounds__(256) void gemm_mfma(const void* __restrict__ Aptr,
                                                 const unsigned short* __restrict__ Bt,
                                                 void* __restrict__ Cptr,
                                                 int K, int Nc, int Mclamp) {
    constexpr int WROWS = 2, WCOLS = 2;
    constexpr int WM = BM / WROWS, WN = BN / WCOLS;
    constexpr int MT = WM / 16, NT = WN / 16;
    constexpr int LDA = BK + 8;
    constexpr int KV = BK / 8;

    __shared__ unsigned short lds_a[BM * LDA];
    __shared__ unsigned short lds_b[BN * LDA];

    const int tid  = threadIdx.x;
    const int wid  = tid >> 6, lane = tid & 63;
    const int wrow = wid >> 1, wcol = wid & 1;
    const int bm = blockIdx.x * BM, bn = blockIdx.y * BN;
    const int r = lane & 15, q = lane >> 4;

    const float*          Af = (const float*)Aptr;
    const unsigned short* Ab = (const unsigned short*)Aptr;

    f32x4 acc[MT][NT];
    f32x4 zero = {0.f, 0.f, 0.f, 0.f};
#pragma unroll
    for (int mi = 0; mi < MT; mi++)
#pragma unroll
        for (int ni = 0; ni < NT; ni++) acc[mi][ni] = zero;

    for (int k0 = 0; k0 < K; k0 += BK) {
#pragma unroll
        for (int it = 0; it < (BM * KV) / 256; it++) {
            int v = tid + it * 256;
            int row = v / KV, kc = (v % KV) * 8;
            int grow = bm + row;
            uint4 d;
            if constexpr (A_F32) {
                grow = (grow <= Mclamp) ? grow : Mclamp;
                const float4* pp = (const float4*)(Af + (size_t)grow * K + k0 + kc);
                float4 f0 = pp[0], f1 = pp[1];
                d.x = (unsigned)f2bf(f0.x) | ((unsigned)f2bf(f0.y) << 16);
                d.y = (unsigned)f2bf(f0.z) | ((unsigned)f2bf(f0.w) << 16);
                d.z = (unsigned)f2bf(f1.x) | ((unsigned)f2bf(f1.y) << 16);
                d.w = (unsigned)f2bf(f1.z) | ((unsigned)f2bf(f1.w) << 16);
            } else {
                d = *(const uint4*)(Ab + (size_t)grow * K + k0 + kc);
            }
            *(uint4*)&lds_a[row * LDA + kc] = d;
        }
#pragma unroll
        for (int it = 0; it < (BN * KV) / 256; it++) {
            int v = tid + it * 256;
            int row = v / KV, kc = (v % KV) * 8;
            uint4 d = *(const uint4*)(Bt + (size_t)(bn + row) * K + k0 + kc);
            *(uint4*)&lds_b[row * LDA + kc] = d;
        }
        __syncthreads();

#pragma unroll
        for (int kk = 0; kk < BK; kk += 32) {
            bf16x8 av[MT], bv[NT];
#pragma unroll
            for (int mi = 0; mi < MT; mi++)
                av[mi] = *(const bf16x8*)&lds_a[(wrow * WM + mi * 16 + r) * LDA + kk + q * 8];
#pragma unroll
            for (int ni = 0; ni < NT; ni++)
                bv[ni] = *(const bf16x8*)&lds_b[(wcol * WN + ni * 16 + r) * LDA + kk + q * 8];
#pragma unroll
            for (int mi = 0; mi < MT; mi++)
#pragma unroll
                for (int ni = 0; ni < NT; ni++)
                    acc[mi][ni] = __builtin_amdgcn_mfma_f32_16x16x32_bf16(av[mi], bv[ni], acc[mi][ni], 0, 0, 0);
        }
        __syncthreads();
    }

    // epilogue: C/D layout col = lane&15, row = q*4 + d
#pragma unroll
    for (int mi = 0; mi < MT; mi++) {
        int row = bm + wrow * WM + mi * 16 + q * 4;
#pragma unroll
        for (int ni = 0; ni < NT; ni++) {
            int cc = bn + wcol * WN + ni * 16 + r;
#pragma unroll
            for (int d = 0; d < 4; d++) {
                if constexpr (OUT == 0) {
                    ((unsigned short*)Cptr)[(size_t)(row + d) * Nc + cc] = f2bf(acc[mi][ni][d]);
                } else {
                    ((unsigned char*)Cptr)[(size_t)(row + d) * Nc + cc] = f2fp8(acc[mi][ni][d]);
                }
            }
        }
    }
}

// ---------- SPMM (F=256, fp8 Z): wave per row, lane owns 4 features ----------
__global__ __launch_bounds__(256) void spmm_f256_fp8(const int* __restrict__ rp, const int2* __restrict__ cpack,
                                                     const unsigned char* __restrict__ Z8,
                                                     const float* __restrict__ bias, unsigned short* __restrict__ H, int N) {
    int w = (blockIdx.x * 256 + threadIdx.x) >> 6;
    if (w >= N) return;
    int lane = threadIdx.x & 63;
    int f4 = lane * 4;                       // byte offset into 256-B fp8 row
    int s = rp[w], e = rp[w + 1];
    float a0 = 0.f, a1 = 0.f, a2 = 0.f, a3 = 0.f;
    int j = s;
    for (; j + 8 <= e; j += 8) {
        const int4* ep = (const int4*)(cpack + j);
        int4 p0 = ep[0], p1 = ep[1], p2 = ep[2], p3 = ep[3];
        unsigned z0 = *(const unsigned*)(Z8 + (size_t)(p0.x & COLMASK) * 256 + f4);
        unsigned z1 = *(const unsigned*)(Z8 + (size_t)(p0.z & COLMASK) * 256 + f4);
        unsigned z2 = *(const unsigned*)(Z8 + (size_t)(p1.x & COLMASK) * 256 + f4);
        unsigned z3 = *(const unsigned*)(Z8 + (size_t)(p1.z & COLMASK) * 256 + f4);
        unsigned z4 = *(const unsigned*)(Z8 + (size_t)(p2.x & COLMASK) * 256 + f4);
        unsigned z5 = *(const unsigned*)(Z8 + (size_t)(p2.z & COLMASK) * 256 + f4);
        unsigned z6 = *(const unsigned*)(Z8 + (size_t)(p3.x & COLMASK) * 256 + f4);
        unsigned z7 = *(const unsigned*)(Z8 + (size_t)(p3.z & COLMASK) * 256 + f4);
        float w0 = __int_as_float(p0.y), w1 = __int_as_float(p0.w);
        float w2 = __int_as_float(p1.y), w3 = __int_as_float(p1.w);
        float w4 = __int_as_float(p2.y), w5 = __int_as_float(p2.w);
        float w6 = __int_as_float(p3.y), w7 = __int_as_float(p3.w);
#define ACC8(Z, W) { \
        f32x2 lo = __builtin_amdgcn_cvt_pk_f32_fp8((int)(Z), false); \
        f32x2 hi = __builtin_amdgcn_cvt_pk_f32_fp8((int)(Z), true);  \
        a0 += (W) * lo.x; a1 += (W) * lo.y; a2 += (W) * hi.x; a3 += (W) * hi.y; }
        ACC8(z0, w0) ACC8(z1, w1) ACC8(z2, w2) ACC8(z3, w3)
        ACC8(z4, w4) ACC8(z5, w5) ACC8(z6, w6) ACC8(z7, w7)
    }
    if (j < e) {
#pragma unroll
        for (int t = 0; t < 8; t++) {
            int jj = j + t;
            int2 ed = (jj < e) ? cpack[jj] : make_int2(0, 0);
            float wt = __int_as_float(ed.y);
            unsigned z = *(const unsigned*)(Z8 + (size_t)(ed.x & COLMASK) * 256 + f4);
            ACC8(z, wt)
        }
    }
#undef ACC8
    float4 b = *(const float4*)(bias + f4);
    a0 = fmaxf(a0 + b.x, 0.f); a1 = fmaxf(a1 + b.y, 0.f);
    a2 = fmaxf(a2 + b.z, 0.f); a3 = fmaxf(a3 + b.w, 0.f);
    ushort4 o; o.x = f2bf(a0); o.y = f2bf(a1); o.z = f2bf(a2); o.w = f2bf(a3);
    *(ushort4*)(H + (size_t)w * 256 + f4) = o;
}

// ---------- SPMM (F=64, bf16 Z) + bias + log_softmax: 4 edges per gather instr ----------
__global__ __launch_bounds__(256) void spmm_f64_lsm(const int* __restrict__ rp, const int2* __restrict__ cpack,
                                                    const unsigned short* __restrict__ Z,
                                                    const float* __restrict__ bias, float* __restrict__ out, int N) {
    int w = (blockIdx.x * 256 + threadIdx.x) >> 6;
    if (w >= N) return;
    int lane = threadIdx.x & 63;
    int g = lane >> 4, fl = lane & 15;
    int s = rp[w], e = rp[w + 1];
    float a0 = 0.f, a1 = 0.f, a2 = 0.f, a3 = 0.f;
    for (int j = s; j < e; j += 8) {
        int j0 = j + g, j1 = j + 4 + g;
        int2 e0 = (j0 < e) ? cpack[j0] : make_int2(0, 0);
        int2 e1 = (j1 < e) ? cpack[j1] : make_int2(0, 0);
        ushort4 z0 = *(const ushort4*)(Z + (size_t)(e0.x & COLMASK) * 64 + fl * 4);
        ushort4 z1 = *(const ushort4*)(Z + (size_t)(e1.x & COLMASK) * 64 + fl * 4);
        float w0 = __int_as_float(e0.y), w1 = __int_as_float(e1.y);
        a0 += w0 * bf2f(z0.x); a1 += w0 * bf2f(z0.y); a2 += w0 * bf2f(z0.z); a3 += w0 * bf2f(z0.w);
        a0 += w1 * bf2f(z1.x); a1 += w1 * bf2f(z1.y); a2 += w1 * bf2f(z1.z); a3 += w1 * bf2f(z1.w);
    }
    a0 += __shfl_xor(a0, 16, 64); a1 += __shfl_xor(a1, 16, 64);
    a2 += __shfl_xor(a2, 16, 64); a3 += __shfl_xor(a3, 16, 64);
    a0 += __shfl_xor(a0, 32, 64); a1 += __shfl_xor(a1, 32, 64);
    a2 += __shfl_xor(a2, 32, 64); a3 += __shfl_xor(a3, 32, 64);
    float4 b = *(const float4*)(bias + fl * 4);
    a0 += b.x; a1 += b.y; a2 += b.z; a3 += b.w;
    float m = fmaxf(fmaxf(a0, a1), fmaxf(a2, a3));
    for (int off = 1; off <= 8; off <<= 1) m = fmaxf(m, __shfl_xor(m, off, 64));
    float sum = __expf(a0 - m) + __expf(a1 - m) + __expf(a2 - m) + __expf(a3 - m);
    for (int off = 1; off <= 8; off <<= 1) sum += __shfl_xor(sum, off, 64);
    float lse = m + __logf(sum);
    if (g == 0) {
        float4 o = make_float4(a0 - lse, a1 - lse, a2 - lse, a3 - lse);
        *(float4*)(out + (size_t)w * 64 + fl * 4) = o;
    }
}

// ---------- launch ----------
extern "C" void kernel_launch(void* const* d_in, const int* in_sizes, int n_in,
                              void* d_out, int out_size, void* d_ws, size_t ws_size,
                              hipStream_t stream) {
    const float* x  = (const float*)d_in[0];
    const int*   er = (const int*)  d_in[1];
    const int*   ec = (const int*)  d_in[2];
    const float* ev = (const float*)d_in[3];
    const float* W1 = (const float*)d_in[4];
    const float* b1 = (const float*)d_in[5];
    const float* W2 = (const float*)d_in[6];
    const float* b2 = (const float*)d_in[7];
    const float* W3 = (const float*)d_in[8];
    const float* b3 = (const float*)d_in[9];

    const int N = N_NODES, E = N_EDGES;

    char* p = (char*)d_ws;
    auto alloc = [&](size_t bytes) -> char* {
        char* q = p; p += (bytes + 255) & ~(size_t)255; return q;
    };
    unsigned short* Wt1    = (unsigned short*)alloc((size_t)256 * 512 * 2);
    unsigned short* Wt2    = (unsigned short*)alloc((size_t)256 * 256 * 2);
    unsigned short* Wt3    = (unsigned short*)alloc((size_t)64  * 256 * 2);
    int*            rp     = (int*)  alloc((size_t)(N + 1) * 4);
    int*            blkCnt = (int*)  alloc((size_t)NBLK * NB * 4);
    int*            blkOff = (int*)  alloc((size_t)NBLK * NB * 4);
    int*            bktTot = (int*)  alloc((size_t)NB * 4);
    int*            bktSt  = (int*)  alloc((size_t)(NB + 1) * 4);
    int2*           cpack  = (int2*) alloc((size_t)E * 8);
    unsigned char*  Z8     = (unsigned char*) alloc((size_t)MPAD * 256);      // fp8 Z (layers 1-2)
    unsigned short* bufA   = (unsigned short*)alloc((size_t)MPAD * 256 * 2);  // bf16 Z (layer 3) / cpackT overlay
    unsigned short* bufB   = (unsigned short*)alloc((size_t)MPAD * 256 * 2);  // bf16 H
    int2*           cpackT = (int2*)bufA;   // overlay: bufA unused until gemm3

    // CSR build
    bucket_hist   <<<NBLK, 256, 0, stream>>>(er, blkCnt);
    bucket_scan_a <<<NB,   256, 0, stream>>>(blkCnt, blkOff, bktTot);
    bucket_scan_b <<<1,   1024, 0, stream>>>(bktTot, bktSt, rp, E);
    bucket_scatter<<<NBLK, 256, 0, stream>>>(er, ec, ev, blkOff, bktSt, cpackT);
    bucket_sort   <<<NB,   256, 0, stream>>>(cpackT, bktSt, cpack, rp);

    // weights -> bf16 transposed (one launch)
    transpose_all<<<(512*256 + 256*256 + 256*64 + 255) / 256, 256, 0, stream>>>(W1, Wt1, W2, Wt2, W3, Wt3);

    // layer 1: Z8 = fp8(x @ W1) ; H = relu(spmm(Z8) + b1)
    gemm_mfma<64, 256, 64, true , 1><<<dim3(MPAD / 64, 1), 256, 0, stream>>>(x,    Wt1, Z8,   512, 256, N - 1);
    spmm_f256_fp8<<<N / 4, 256, 0, stream>>>(rp, cpack, Z8, b1, bufB, N);
    // layer 2
    gemm_mfma<64, 256, 64, false, 1><<<dim3(MPAD / 64, 1), 256, 0, stream>>>(bufB, Wt2, Z8,   256, 256, N - 1);
    spmm_f256_fp8<<<N / 4, 256, 0, stream>>>(rp, cpack, Z8, b2, bufB, N);
    // layer 3 (bf16 Z to protect logits) + fused bias + log_softmax
    gemm_mfma<128, 64, 64, false, 0><<<dim3(MPAD / 128, 1), 256, 0, stream>>>(bufB, Wt3, bufA, 256, 64, N - 1);
    spmm_f64_lsm<<<N / 4, 256, 0, stream>>>(rp, cpack, bufA, b3, (float*)d_out, N);
}